// Round 10
// baseline (694.535 us; speedup 1.0000x reference)
//
#include <hip/hip_runtime.h>
#include <hip/hip_bf16.h>
#include <stdint.h>

#define HDIM 128
#define SBITS 10
#define SBMAX 128  // supports N <= 131072

typedef __attribute__((ext_vector_type(8))) short short8;
typedef __attribute__((ext_vector_type(4))) float f32x4;

__device__ __forceinline__ ushort f2bf(float f) {
  uint u = __float_as_uint(f);
  u = (u + 0x7fffu + ((u >> 16) & 1u)) >> 16;
  return (ushort)u;
}
__device__ __forceinline__ float bflo(uint v) { return __uint_as_float(v << 16); }
__device__ __forceinline__ float bfhi(uint v) { return __uint_as_float(v & 0xffff0000u); }

// padded degree: deg = cnt+1 padded to multiple of 4
__device__ __forceinline__ int pdeg4(int c) { return (c + 4) & ~3; }

// packed colw entry: src (17 bits) | bf15 weight << 17 (weight in (0,1])
__device__ __forceinline__ uint pack_cw(int src, float w) {
  uint w15 = (__float_as_uint(w) + 0x8000u) >> 16;
  return (uint)src | (w15 << 17);
}
__device__ __forceinline__ uint cw_src(uint u) { return u & 0x1FFFFu; }
__device__ __forceinline__ float cw_w(uint u) { return __uint_as_float((u >> 17) << 16); }

// ---------------- setup: CSR build (R9 structure, unchanged) ----------------

__global__ __launch_bounds__(256) void bucket_edges(const int* __restrict__ ei,
                                                    int* __restrict__ bktcur,
                                                    uint* __restrict__ bkt, int E,
                                                    int cap) {
  __shared__ int hist[SBMAX], base[SBMAX];
  const int t = threadIdx.x;
  const int c0 = blockIdx.x * 2048;
  for (int i = t; i < SBMAX; i += 256) hist[i] = 0;
  __syncthreads();
  uint pk[8];
  int sb_[8], rk[8];
#pragma unroll
  for (int j = 0; j < 8; ++j) {
    int idx = c0 + j * 256 + t;
    sb_[j] = -1;
    if (idx < E) {
      int s = ei[idx];
      int d = ei[E + idx];
      int b = d >> SBITS;
      pk[j] = (uint)(d & 1023) | ((uint)s << SBITS);
      sb_[j] = b;
      rk[j] = atomicAdd(&hist[b], 1);
    }
  }
  __syncthreads();
  for (int i = t; i < SBMAX; i += 256)
    base[i] = hist[i] ? atomicAdd(&bktcur[i * 16], hist[i]) : 0;
  __syncthreads();
#pragma unroll
  for (int j = 0; j < 8; ++j)
    if (sb_[j] >= 0)
      bkt[(size_t)sb_[j] * cap + base[sb_[j]] + rk[j]] = pk[j];
}

__global__ __launch_bounds__(256) void csr_count(const uint* __restrict__ bkt,
                                                 const int* __restrict__ bktcur,
                                                 float* __restrict__ dis,
                                                 int* __restrict__ sbtot, int cap,
                                                 int N) {
  __shared__ int cnt[1024];
  __shared__ int red[256];
  const int sb = blockIdx.x, t = threadIdx.x;
  const int n0 = sb << SBITS;
  const int ecnt = bktcur[sb * 16];
  const uint* eb = bkt + (size_t)sb * cap;
  for (int i = t; i < 1024; i += 256) cnt[i] = 0;
  __syncthreads();
  for (int i = t; i < ecnt; i += 256)
    atomicAdd(&cnt[__builtin_nontemporal_load(eb + i) & 1023], 1);
  __syncthreads();
  int s = 0;
#pragma unroll
  for (int j = 0; j < 4; ++j) {
    int idx = t * 4 + j, n = n0 + idx;
    if (n < N) {
      dis[n] = rsqrtf((float)(cnt[idx] + 1));
      s += pdeg4(cnt[idx]);
    }
  }
  red[t] = s;
  __syncthreads();
  for (int off = 128; off; off >>= 1) {
    if (t < off) red[t] += red[t + off];
    __syncthreads();
  }
  if (t == 0) sbtot[sb] = red[0];
}

__global__ __launch_bounds__(128) void scan_sb(const int* __restrict__ sbtot,
                                               int* __restrict__ sbbase,
                                               int* __restrict__ rowptr, int SB,
                                               int N) {
  __shared__ int sh[128];
  int t = threadIdx.x;
  int v = (t < SB) ? sbtot[t] : 0;
  sh[t] = v;
  __syncthreads();
  for (int off = 1; off < 128; off <<= 1) {
    int add = (t >= off) ? sh[t - off] : 0;
    __syncthreads();
    sh[t] += add;
    __syncthreads();
  }
  if (t < SB) sbbase[t] = sh[t] - v;
  if (t == 127) rowptr[N] = sh[127];
}

__global__ __launch_bounds__(256) void csr_place(const uint* __restrict__ bkt,
                                                 const int* __restrict__ bktcur,
                                                 const int* __restrict__ sbbase,
                                                 const float* __restrict__ dis,
                                                 int* __restrict__ rowptr,
                                                 uint* __restrict__ colw, int cap,
                                                 int N) {
  __shared__ int cnt[1024], cur[1024];
  __shared__ int sh[256];
  const int sb = blockIdx.x, t = threadIdx.x;
  const int n0 = sb << SBITS;
  const int ecnt = bktcur[sb * 16];
  const uint* eb = bkt + (size_t)sb * cap;
  const int base = sbbase[sb];
  for (int i = t; i < 1024; i += 256) cnt[i] = 0;
  __syncthreads();
  for (int i = t; i < ecnt; i += 256)
    atomicAdd(&cnt[__builtin_nontemporal_load(eb + i) & 1023], 1);
  __syncthreads();
  int v[4], tsum = 0;
#pragma unroll
  for (int j = 0; j < 4; ++j) {
    int idx = t * 4 + j, n = n0 + idx;
    v[j] = (n < N) ? pdeg4(cnt[idx]) : 0;
    tsum += v[j];
  }
  sh[t] = tsum;
  __syncthreads();
  for (int off = 1; off < 256; off <<= 1) {
    int add = (t >= off) ? sh[t - off] : 0;
    __syncthreads();
    sh[t] += add;
    __syncthreads();
  }
  int p = sh[t] - tsum;
#pragma unroll
  for (int j = 0; j < 4; ++j) {
    int idx = t * 4 + j, n = n0 + idx;
    if (n < N) {
      rowptr[n] = base + p;
      cur[idx] = p + 1;  // self-loop occupies slot p
      float dn = dis[n];
      colw[base + p] = pack_cw(n, dn * dn);
      int deg = cnt[idx];
      for (int q = deg + 1; q < v[j]; ++q) colw[base + p + q] = (uint)n;  // pads
    }
    p += v[j];
  }
  __syncthreads();
  for (int i = t; i < ecnt; i += 256) {
    uint u = __builtin_nontemporal_load(eb + i);
    int dloc = (int)(u & 1023);
    int s2 = (int)(u >> SBITS);
    int pos = atomicAdd(&cur[dloc], 1);  // LDS cursor
    int d = n0 + dloc;
    colw[base + pos] = pack_cw(s2, dis[s2] * dis[d]);
  }
}

// Pre-swizzle Ws into MFMA B-fragment order per layer
__global__ __launch_bounds__(256) void swz_w(const float* __restrict__ Ws,
                                             ushort* __restrict__ Wsw, int total) {
  int idx = blockIdx.x * 256 + threadIdx.x;
  if (idx >= total) return;
  int l = idx >> 14, r = idx & 16383;
  int j = r & 7, lane = (r >> 3) & 63, kk = (r >> 9) & 3, c = r >> 11;
  int n = c * 16 + (lane & 15);
  int k = kk * 32 + (lane >> 4) * 8 + j;
  Wsw[idx] = f2bf(Ws[l * 16384 + k * HDIM + n]);
}

__global__ __launch_bounds__(256) void cvt_x(const float* __restrict__ x,
                                             ushort* __restrict__ xb, int total) {
  int i = (blockIdx.x * 256 + threadIdx.x) * 4;
  if (i < total) {
    float4 v = *(const float4*)(x + i);
    uint2 o;
    o.x = (uint)f2bf(v.x) | ((uint)f2bf(v.y) << 16);
    o.y = (uint)f2bf(v.z) | ((uint)f2bf(v.w) << 16);
    *(uint2*)(xb + i) = o;
  }
}

// ---------------- fused layer: x' = relu((A x) W + b) ----------------
// Phase 1: 64-node Z-tile aggregated into LDS (wave = 16 nodes, 2-node-deep
// pipeline, 24-edge bursts per node, lane = e*16+c, full 256B row gathers).
// Phase 2: Z @ W on MFMA (W staged in LDS at block start), bias+relu epilogue,
// coalesced bf16 store. Cross-block overlap: one block's MFMA hides another's
// gather latency (3 blocks/CU).

__device__ __forceinline__ void issue_node(const ushort* __restrict__ Xin,
                                           const uint* __restrict__ colw,
                                           const int* __restrict__ rowptr,
                                           int node, int N, int e, int c,
                                           uint (&cw)[6], uint4 (&gv)[6],
                                           int& beg, int& pd) {
  if (node < N) {
    beg = rowptr[node];
    pd = rowptr[node + 1] - beg;
  } else {
    beg = 0;
    pd = 0;
  }
  const int last = pd > 0 ? pd - 1 : 0;
#pragma unroll
  for (int k = 0; k < 6; ++k) {
    int off = 4 * k + e;
    cw[k] = pd ? __builtin_nontemporal_load(colw + beg + (off < pd ? off : last))
               : 0u;
  }
#pragma unroll
  for (int k = 0; k < 6; ++k)
    gv[k] = *(const uint4*)(Xin + ((size_t)cw_src(cw[k]) << 7) + c * 8);
}

__device__ __forceinline__ void consume_node(const ushort* __restrict__ Xin,
                                             const uint* __restrict__ colw,
                                             ushort* __restrict__ zlds, int row,
                                             int beg, int pd, int e, int c,
                                             const uint (&cw)[6],
                                             const uint4 (&gv)[6]) {
  float acc[8];
#pragma unroll
  for (int i = 0; i < 8; ++i) acc[i] = 0.f;
#pragma unroll
  for (int k = 0; k < 6; ++k) {
    int off = 4 * k + e;
    float w = (off < pd) ? cw_w(cw[k]) : 0.f;
    uint4 v = gv[k];
    acc[0] += w * bflo(v.x); acc[1] += w * bfhi(v.x);
    acc[2] += w * bflo(v.y); acc[3] += w * bfhi(v.y);
    acc[4] += w * bflo(v.z); acc[5] += w * bfhi(v.z);
    acc[6] += w * bflo(v.w); acc[7] += w * bfhi(v.w);
  }
  for (int off = 24 + e; off < pd; off += 4) {  // tail, deg > 23 (rare)
    uint u = __builtin_nontemporal_load(colw + beg + off);
    uint4 v = *(const uint4*)(Xin + ((size_t)cw_src(u) << 7) + c * 8);
    float w = cw_w(u);
    acc[0] += w * bflo(v.x); acc[1] += w * bfhi(v.x);
    acc[2] += w * bflo(v.y); acc[3] += w * bfhi(v.y);
    acc[4] += w * bflo(v.z); acc[5] += w * bfhi(v.z);
    acc[6] += w * bflo(v.w); acc[7] += w * bfhi(v.w);
  }
#pragma unroll
  for (int i = 0; i < 8; ++i) {
    acc[i] += __shfl_xor(acc[i], 16, 64);
    acc[i] += __shfl_xor(acc[i], 32, 64);
  }
  if (e == 0) {
    uint4 pk;
    pk.x = (uint)f2bf(acc[0]) | ((uint)f2bf(acc[1]) << 16);
    pk.y = (uint)f2bf(acc[2]) | ((uint)f2bf(acc[3]) << 16);
    pk.z = (uint)f2bf(acc[4]) | ((uint)f2bf(acc[5]) << 16);
    pk.w = (uint)f2bf(acc[6]) | ((uint)f2bf(acc[7]) << 16);
    *(uint4*)(zlds + row * 136 + c * 8) = pk;
  }
}

__global__ __launch_bounds__(256, 3) void agg_gemm(
    const ushort* __restrict__ Xin, const uint* __restrict__ colw,
    const int* __restrict__ rowptr, const ushort* __restrict__ Wsw,
    const float* __restrict__ bias, ushort* __restrict__ Xout, int N) {
  __shared__ ushort wlds[16384];    // 32 KB swizzled W
  __shared__ ushort zlds[64 * 136]; // Z-tile / C restage, padded stride
  const int t = threadIdx.x;
  {
    const int4* src = (const int4*)Wsw;
    int4* dst = (int4*)wlds;
#pragma unroll
    for (int i = 0; i < 8; ++i) dst[t + 256 * i] = src[t + 256 * i];
  }
  const int wave = t >> 6, lane = t & 63;
  const int e = lane >> 4, c = lane & 15;
  const int nbase = blockIdx.x * 64 + wave * 16;

  // ---- phase 1: aggregate 16 nodes/wave, 2-node software pipeline ----
  uint cwA[6], cwB[6];
  uint4 gvA[6], gvB[6];
  int begA, pdA, begB, pdB;
  issue_node(Xin, colw, rowptr, nbase + 0, N, e, c, cwA, gvA, begA, pdA);
  for (int i = 0; i < 16; i += 2) {
    issue_node(Xin, colw, rowptr, nbase + i + 1, N, e, c, cwB, gvB, begB, pdB);
    consume_node(Xin, colw, zlds, wave * 16 + i, begA, pdA, e, c, cwA, gvA);
    if (i + 2 < 16)
      issue_node(Xin, colw, rowptr, nbase + i + 2, N, e, c, cwA, gvA, begA, pdA);
    consume_node(Xin, colw, zlds, wave * 16 + i + 1, begB, pdB, e, c, cwB, gvB);
  }
  __syncthreads();  // Z-tile + W complete

  // ---- phase 2: Z @ W, bias + relu, store ----
  const int kq = lane >> 4;
  const int arow = wave * 16 + (lane & 15);
  short8 afr[4];
#pragma unroll
  for (int kk = 0; kk < 4; ++kk)
    afr[kk] = *(const short8*)(zlds + arow * 136 + kk * 32 + kq * 8);
  __syncthreads();  // all A-frags read; zlds free for C restage

  f32x4 acc[8];
#pragma unroll
  for (int cc = 0; cc < 8; ++cc) acc[cc] = f32x4{0.f, 0.f, 0.f, 0.f};
#pragma unroll
  for (int kk = 0; kk < 4; ++kk) {
#pragma unroll
    for (int cc = 0; cc < 8; ++cc) {
      short8 bfr = *(const short8*)(wlds + (((cc * 4 + kk) * 64 + lane) << 3));
      acc[cc] = __builtin_amdgcn_mfma_f32_16x16x32_bf16(afr[kk], bfr, acc[cc], 0, 0, 0);
    }
  }

  const int m0 = wave * 16 + kq * 4;
#pragma unroll
  for (int cc = 0; cc < 8; ++cc) {
    int col = cc * 16 + (lane & 15);
    float bv = bias[col];
#pragma unroll
    for (int r = 0; r < 4; ++r)
      zlds[(m0 + r) * 136 + col] = f2bf(fmaxf(acc[cc][r] + bv, 0.f));
  }
  __syncthreads();
#pragma unroll
  for (int i = 0; i < 4; ++i) {
    int idx = t + 256 * i;
    int row = idx >> 4, piece = idx & 15;
    int grow = blockIdx.x * 64 + row;
    if (grow < N)
      ((int4*)Xout)[(size_t)blockIdx.x * 1024 + idx] =
          *(const int4*)(zlds + row * 136 + piece * 8);
  }
}

// ---------------- pooling + head ----------------

__global__ __launch_bounds__(256) void pool_partial(const ushort* __restrict__ x,
                                                    const int* __restrict__ batch,
                                                    float* __restrict__ pooled,
                                                    int* __restrict__ gcnt, int N) {
  const int g = blockIdx.x, s = blockIdx.y;  // gridDim.y = 8 splits
  const int t = threadIdx.x;
  __shared__ int range[2];
  __shared__ float sums[256];
  if (t < 2) {
    int target = g + t;
    int lo = 0, hi = N;
    while (lo < hi) {
      int mid = (lo + hi) >> 1;
      if (batch[mid] < target) lo = mid + 1;
      else hi = mid;
    }
    range[t] = lo;
  }
  __syncthreads();
  int beg = range[0], end = range[1];
  if (s == 0 && t == 0) gcnt[g] = end - beg;
  int col = t & 127, half = t >> 7;
  float acc = 0.f;
  for (int n = beg + s * 2 + half; n < end; n += 16) {
    acc += __uint_as_float(((uint)x[(size_t)n * HDIM + col]) << 16);
  }
  sums[t] = acc;
  __syncthreads();
  if (t < 128) atomicAdd(&pooled[g * HDIM + t], sums[t] + sums[t + 128]);
}

__global__ __launch_bounds__(256) void out_final(const float* __restrict__ pooled,
                                                 const int* __restrict__ gcnt,
                                                 const float* __restrict__ W_out,
                                                 const float* __restrict__ b_out,
                                                 float* __restrict__ out, int G, int C) {
  int i = blockIdx.x * 256 + threadIdx.x;
  if (i >= G * C) return;
  int g = i / C, c = i - g * C;
  float inv = 1.f / (float)max(gcnt[g], 1);
  const float* pg = pooled + g * HDIM;
  float o = 0.f;
  for (int h = 0; h < HDIM; ++h) o += pg[h] * W_out[h * C + c];
  out[i] = b_out[c] + o * inv;
}

// ---------------- host ----------------

extern "C" void kernel_launch(void* const* d_in, const int* in_sizes, int n_in,
                              void* d_out, int out_size, void* d_ws, size_t ws_size,
                              hipStream_t stream) {
  (void)n_in;
  (void)ws_size;
  const float* x = (const float*)d_in[0];
  const int* ei = (const int*)d_in[1];
  const int* batch = (const int*)d_in[2];
  const float* Ws = (const float*)d_in[4];
  const float* bs = (const float*)d_in[5];
  const float* W_out = (const float*)d_in[6];
  const float* b_out = (const float*)d_in[7];
  float* out = (float*)d_out;

  const int N = in_sizes[0] / HDIM;
  const int E = in_sizes[1] / 2;
  const int L = in_sizes[5] / HDIM;
  const int C = in_sizes[7];
  const int G = out_size / C;
  const int SB = (N + 1023) >> SBITS;
  const int cap = E / SB + 8192;

  char* p = (char*)d_ws;
  auto carve = [&](size_t bytes) {
    char* r = p;
    p += (bytes + 255) & ~(size_t)255;
    return r;
  };
  int* bktcur = (int*)carve(SBMAX * 64);
  float* dis = (float*)carve((size_t)N * 4);
  int* rowptr = (int*)carve((size_t)(N + 1) * 4);
  int* sbtot = (int*)carve(SBMAX * 4);
  int* sbbase = (int*)carve(SBMAX * 4);
  uint* bkt = (uint*)carve((size_t)SB * cap * 4);
  uint* colw = (uint*)carve(((size_t)E + 4 * (size_t)N + 64) * 4);
  ushort* Wsw = (ushort*)carve((size_t)L * HDIM * HDIM * 2);
  ushort* xa = (ushort*)carve((size_t)N * HDIM * 2);
  ushort* y0 = (ushort*)carve((size_t)N * HDIM * 2);
  ushort* y1 = (ushort*)carve((size_t)N * HDIM * 2);
  float* pooled = (float*)carve((size_t)G * HDIM * 4 + (size_t)G * 4);
  int* gcnt = (int*)(pooled + (size_t)G * HDIM);

  hipMemsetAsync(bktcur, 0, SBMAX * 64, stream);
  hipMemsetAsync(pooled, 0, (size_t)G * HDIM * 4 + (size_t)G * 4, stream);

  bucket_edges<<<(E + 2047) / 2048, 256, 0, stream>>>(ei, bktcur, bkt, E, cap);
  csr_count<<<SB, 256, 0, stream>>>(bkt, bktcur, dis, sbtot, cap, N);
  scan_sb<<<1, 128, 0, stream>>>(sbtot, sbbase, rowptr, SB, N);
  csr_place<<<SB, 256, 0, stream>>>(bkt, bktcur, sbbase, dis, rowptr, colw, cap, N);
  swz_w<<<(L * HDIM * HDIM + 255) / 256, 256, 0, stream>>>(Ws, Wsw, L * HDIM * HDIM);
  cvt_x<<<((N * HDIM / 4) + 255) / 256, 256, 0, stream>>>(x, xa, N * HDIM);

  const int gb = (N + 63) / 64;
  ushort* xc = xa;
  ushort* ybuf[2] = {y0, y1};
  for (int l = 0; l < L; ++l) {
    ushort* xn = ybuf[l & 1];
    agg_gemm<<<gb, 256, 0, stream>>>(xc, colw, rowptr,
                                     Wsw + (size_t)l * HDIM * HDIM,
                                     bs + (size_t)l * HDIM, xn, N);
    xc = xn;
  }
  pool_partial<<<dim3(G, 8), 256, 0, stream>>>(xc, batch, pooled, gcnt, N);
  out_final<<<(G * C + 255) / 256, 256, 0, stream>>>(pooled, gcnt, W_out, b_out, out, G, C);
}